// Round 1
// baseline (7170.531 us; speedup 1.0000x reference)
//
#include <hip/hip_runtime.h>
#include <math.h>

#define N_NODES 100000
#define N_EDGES 3200000
#define D_FEAT 256
#define GC_HID 20
#define DEC_HID 40
#define Z_DIM 32

// ---------------- ws layout (bytes) ----------------
// h_pre : [N*20] f32 @ 0           (8,000,000)   (reused as h2_pre)
// agg1  : [N*20] f32 @  8,000,000  (8,000,000)
// agg2  : [N*20] f32 @ 16,000,000  (8,000,000)
// rs_s  : [N]    f32 @ 24,000,000
// rs_r  : [N]    f32 @ 24,400,000
// deg_s : [N]    u32 @ 24,800,000
// deg_r : [N]    u32 @ 25,200,000
// z     : [N*32] f32 @ 25,600,000  (12,800,000)  end = 38,400,000

__global__ void k_deg(const int* __restrict__ snd, const int* __restrict__ rcv,
                      unsigned* __restrict__ dS, unsigned* __restrict__ dR) {
    int e = blockIdx.x * 256 + threadIdx.x;
    if (e < N_EDGES) {
        atomicAdd(&dS[snd[e]], 1u);
        atomicAdd(&dR[rcv[e]], 1u);
    }
}

__global__ void k_rs(const unsigned* __restrict__ dS, const unsigned* __restrict__ dR,
                     float* __restrict__ rs_s, float* __restrict__ rs_r) {
    int i = blockIdx.x * 256 + threadIdx.x;
    if (i < N_NODES) {
        rs_s[i] = rsqrtf(fmaxf((float)dS[i], 1.0f));
        rs_r[i] = rsqrtf(fmaxf((float)dR[i], 1.0f));
    }
}

// GC layer 1 transform: h_pre[n] = softmax(relu(nodes[n] @ W1 + b1)) * rs_s[n]
// wave-per-node; W1 transposed in LDS for conflict-free b128 reads.
__global__ __launch_bounds__(256) void k_gc1(const float* __restrict__ nodes,
                                             const float* __restrict__ W1,
                                             const float* __restrict__ b1,
                                             const float* __restrict__ rs_s,
                                             float* __restrict__ h_pre) {
    __shared__ float Wt[GC_HID][D_FEAT];
    __shared__ float bsh[GC_HID];
    int tid = threadIdx.x;
    for (int idx = tid; idx < D_FEAT * GC_HID; idx += 256) {
        int i = idx / GC_HID, j = idx - i * GC_HID;
        Wt[j][i] = W1[idx];
    }
    if (tid < GC_HID) bsh[tid] = b1[tid];
    __syncthreads();

    int lane = tid & 63;
    int w    = tid >> 6;
    for (int node = blockIdx.x * 4 + w; node < N_NODES; node += gridDim.x * 4) {
        const float4 x = ((const float4*)nodes)[node * (D_FEAT / 4) + lane];
        float p[GC_HID];
#pragma unroll
        for (int j = 0; j < GC_HID; ++j) {
            float4 wv = ((const float4*)&Wt[j][0])[lane];
            p[j] = x.x * wv.x + x.y * wv.y + x.z * wv.z + x.w * wv.w;
        }
#pragma unroll
        for (int m = 32; m >= 1; m >>= 1) {
#pragma unroll
            for (int j = 0; j < GC_HID; ++j) p[j] += __shfl_xor(p[j], m, 64);
        }
        float mx = -1e30f;
#pragma unroll
        for (int j = 0; j < GC_HID; ++j) {
            p[j] = fmaxf(p[j] + bsh[j], 0.0f);
            mx = fmaxf(mx, p[j]);
        }
        float s = 0.0f;
#pragma unroll
        for (int j = 0; j < GC_HID; ++j) {
            p[j] = __expf(p[j] - mx);
            s += p[j];
        }
        float inv = rs_s[node] / s;
#pragma unroll
        for (int j = 0; j < GC_HID; ++j) p[j] *= inv;
        if (lane == 0) {
            float4* o = (float4*)&h_pre[node * GC_HID];
            o[0] = make_float4(p[0],  p[1],  p[2],  p[3]);
            o[1] = make_float4(p[4],  p[5],  p[6],  p[7]);
            o[2] = make_float4(p[8],  p[9],  p[10], p[11]);
            o[3] = make_float4(p[12], p[13], p[14], p[15]);
            o[4] = make_float4(p[16], p[17], p[18], p[19]);
        }
    }
}

// edge scatter: dst[rcv[e]] += src[snd[e]]  (20 floats per edge)
__global__ void k_scatter(const int* __restrict__ snd, const int* __restrict__ rcv,
                          const float* __restrict__ src, float* __restrict__ dst) {
    int e = blockIdx.x * 256 + threadIdx.x;
    if (e >= N_EDGES) return;
    int s = snd[e], r = rcv[e];
    const float4* sp = (const float4*)&src[s * GC_HID];
    float4 a = sp[0], b = sp[1], c = sp[2], d = sp[3], f = sp[4];
    float* dp = &dst[r * GC_HID];
    atomicAdd(dp + 0,  a.x); atomicAdd(dp + 1,  a.y); atomicAdd(dp + 2,  a.z); atomicAdd(dp + 3,  a.w);
    atomicAdd(dp + 4,  b.x); atomicAdd(dp + 5,  b.y); atomicAdd(dp + 6,  b.z); atomicAdd(dp + 7,  b.w);
    atomicAdd(dp + 8,  c.x); atomicAdd(dp + 9,  c.y); atomicAdd(dp + 10, c.z); atomicAdd(dp + 11, c.w);
    atomicAdd(dp + 12, d.x); atomicAdd(dp + 13, d.y); atomicAdd(dp + 14, d.z); atomicAdd(dp + 15, d.w);
    atomicAdd(dp + 16, f.x); atomicAdd(dp + 17, f.y); atomicAdd(dp + 18, f.z); atomicAdd(dp + 19, f.w);
}

// finish layer1 (h1 = agg1*rs_r) + GC layer 2 transform -> h2_pre (*rs_s)
__global__ __launch_bounds__(256) void k_gc2(const float* __restrict__ agg1,
                                             const float* __restrict__ W2,
                                             const float* __restrict__ b2,
                                             const float* __restrict__ rs_r,
                                             const float* __restrict__ rs_s,
                                             float* __restrict__ h2_pre) {
    __shared__ float Wsh[GC_HID * GC_HID];
    __shared__ float bsh[GC_HID];
    int tid = threadIdx.x;
    if (tid < GC_HID * GC_HID) Wsh[tid] = W2[tid];
    if (tid < GC_HID) bsh[tid] = b2[tid];
    __syncthreads();
    int node = blockIdx.x * 256 + tid;
    if (node >= N_NODES) return;
    float sc = rs_r[node];
    const float4* ap = (const float4*)&agg1[node * GC_HID];
    float4 a0 = ap[0], a1 = ap[1], a2 = ap[2], a3 = ap[3], a4 = ap[4];
    float h1[GC_HID] = {a0.x,a0.y,a0.z,a0.w, a1.x,a1.y,a1.z,a1.w,
                        a2.x,a2.y,a2.z,a2.w, a3.x,a3.y,a3.z,a3.w,
                        a4.x,a4.y,a4.z,a4.w};
#pragma unroll
    for (int i = 0; i < GC_HID; ++i) h1[i] *= sc;
    float t[GC_HID];
#pragma unroll
    for (int j = 0; j < GC_HID; ++j) t[j] = bsh[j];
#pragma unroll
    for (int i = 0; i < GC_HID; ++i) {
        float x = h1[i];
#pragma unroll
        for (int j = 0; j < GC_HID; ++j) t[j] = fmaf(x, Wsh[i * GC_HID + j], t[j]);
    }
    float mx = -1e30f;
#pragma unroll
    for (int j = 0; j < GC_HID; ++j) { t[j] = fmaxf(t[j], 0.0f); mx = fmaxf(mx, t[j]); }
    float s = 0.0f;
#pragma unroll
    for (int j = 0; j < GC_HID; ++j) { t[j] = __expf(t[j] - mx); s += t[j]; }
    float inv = rs_s[node] / s;
#pragma unroll
    for (int j = 0; j < GC_HID; ++j) t[j] *= inv;
    float4* o = (float4*)&h2_pre[node * GC_HID];
    o[0] = make_float4(t[0],  t[1],  t[2],  t[3]);
    o[1] = make_float4(t[4],  t[5],  t[6],  t[7]);
    o[2] = make_float4(t[8],  t[9],  t[10], t[11]);
    o[3] = make_float4(t[12], t[13], t[14], t[15]);
    o[4] = make_float4(t[16], t[17], t[18], t[19]);
}

// encoder head: h2 = agg2*rs_r; hcat=[h2, nodes]; mu/logsig2 = hcat@W+b; z
__global__ __launch_bounds__(256) void k_enc(const float* __restrict__ agg2,
                                             const float* __restrict__ nodes,
                                             const float* __restrict__ eps,
                                             const float* __restrict__ Wmu,
                                             const float* __restrict__ bmu,
                                             const float* __restrict__ Wls,
                                             const float* __restrict__ bls,
                                             const float* __restrict__ rs_r,
                                             float* __restrict__ mu_out,
                                             float* __restrict__ ls_out,
                                             float* __restrict__ z) {
    int node = blockIdx.x * 256 + threadIdx.x;
    if (node >= N_NODES) return;
    float accm[Z_DIM], accl[Z_DIM];
#pragma unroll
    for (int j = 0; j < Z_DIM; ++j) { accm[j] = bmu[j]; accl[j] = bls[j]; }

    float sc = rs_r[node];
    const float4* ap = (const float4*)&agg2[node * GC_HID];
    float4 a0 = ap[0], a1 = ap[1], a2 = ap[2], a3 = ap[3], a4 = ap[4];
    float h2[GC_HID] = {a0.x,a0.y,a0.z,a0.w, a1.x,a1.y,a1.z,a1.w,
                        a2.x,a2.y,a2.z,a2.w, a3.x,a3.y,a3.z,a3.w,
                        a4.x,a4.y,a4.z,a4.w};
#pragma unroll
    for (int i = 0; i < GC_HID; ++i) {
        float x = h2[i] * sc;
#pragma unroll
        for (int j = 0; j < Z_DIM; ++j) {
            accm[j] = fmaf(x, Wmu[i * Z_DIM + j], accm[j]);
            accl[j] = fmaf(x, Wls[i * Z_DIM + j], accl[j]);
        }
    }
    const float4* np = (const float4*)&nodes[node * D_FEAT];
    for (int i4 = 0; i4 < D_FEAT / 4; ++i4) {
        float4 xx = np[i4];
        int row = GC_HID + i4 * 4;
#pragma unroll
        for (int c = 0; c < 4; ++c) {
            float x = (c == 0) ? xx.x : (c == 1) ? xx.y : (c == 2) ? xx.z : xx.w;
#pragma unroll
            for (int j = 0; j < Z_DIM; ++j) {
                accm[j] = fmaf(x, Wmu[(row + c) * Z_DIM + j], accm[j]);
                accl[j] = fmaf(x, Wls[(row + c) * Z_DIM + j], accl[j]);
            }
        }
    }
    const float4* ep = (const float4*)&eps[node * Z_DIM];
    float4* mo = (float4*)&mu_out[node * Z_DIM];
    float4* lo = (float4*)&ls_out[node * Z_DIM];
    float4* zo = (float4*)&z[node * Z_DIM];
#pragma unroll
    for (int q = 0; q < Z_DIM / 4; ++q) {
        float4 ev = ep[q];
        float4 m4 = make_float4(accm[4*q], accm[4*q+1], accm[4*q+2], accm[4*q+3]);
        float4 l4 = make_float4(accl[4*q], accl[4*q+1], accl[4*q+2], accl[4*q+3]);
        mo[q] = m4;
        lo[q] = l4;
        float4 zz;
        zz.x = m4.x + (1e-4f + __expf(0.5f * l4.x)) * ev.x;
        zz.y = m4.y + (1e-4f + __expf(0.5f * l4.y)) * ev.y;
        zz.z = m4.z + (1e-4f + __expf(0.5f * l4.z)) * ev.z;
        zz.w = m4.w + (1e-4f + __expf(0.5f * l4.w)) * ev.w;
        zo[q] = zz;
    }
}

// decoder: d = relu(z@Wd1+bd1); X = d@Wd2+bd2
__global__ __launch_bounds__(256) void k_dec(const float* __restrict__ z,
                                             const float* __restrict__ Wd1,
                                             const float* __restrict__ bd1,
                                             const float* __restrict__ Wd2,
                                             const float* __restrict__ bd2,
                                             float* __restrict__ X) {
    int node = blockIdx.x * 256 + threadIdx.x;
    if (node >= N_NODES) return;
    float zv[Z_DIM];
    const float4* zp = (const float4*)&z[node * Z_DIM];
#pragma unroll
    for (int q = 0; q < Z_DIM / 4; ++q) {
        float4 v = zp[q];
        zv[4*q] = v.x; zv[4*q+1] = v.y; zv[4*q+2] = v.z; zv[4*q+3] = v.w;
    }
    float d[DEC_HID];
#pragma unroll
    for (int j = 0; j < DEC_HID; ++j) d[j] = bd1[j];
#pragma unroll
    for (int i = 0; i < Z_DIM; ++i) {
        float x = zv[i];
#pragma unroll
        for (int j = 0; j < DEC_HID; ++j) d[j] = fmaf(x, Wd1[i * DEC_HID + j], d[j]);
    }
#pragma unroll
    for (int j = 0; j < DEC_HID; ++j) d[j] = fmaxf(d[j], 0.0f);

    float4* xp = (float4*)&X[node * D_FEAT];
    for (int ch = 0; ch < 4; ++ch) {          // 4 chunks of 64 outputs
        float o[64];
#pragma unroll
        for (int j = 0; j < 64; ++j) o[j] = bd2[ch * 64 + j];
#pragma unroll
        for (int i = 0; i < DEC_HID; ++i) {
            float x = d[i];
#pragma unroll
            for (int j = 0; j < 64; ++j)
                o[j] = fmaf(x, Wd2[i * 256 + ch * 64 + j], o[j]);
        }
#pragma unroll
        for (int q = 0; q < 16; ++q)
            xp[ch * 16 + q] = make_float4(o[4*q], o[4*q+1], o[4*q+2], o[4*q+3]);
    }
}

extern "C" void kernel_launch(void* const* d_in, const int* in_sizes, int n_in,
                              void* d_out, int out_size, void* d_ws, size_t ws_size,
                              hipStream_t stream) {
    const float* nodes = (const float*)d_in[0];
    const int*   snd   = (const int*)d_in[1];
    const int*   rcv   = (const int*)d_in[2];
    const float* eps   = (const float*)d_in[3];
    const float* W1    = (const float*)d_in[4];
    const float* b1    = (const float*)d_in[5];
    const float* W2    = (const float*)d_in[6];
    const float* b2    = (const float*)d_in[7];
    const float* Wmu   = (const float*)d_in[8];
    const float* bmu   = (const float*)d_in[9];
    const float* Wls   = (const float*)d_in[10];
    const float* bls   = (const float*)d_in[11];
    const float* Wd1   = (const float*)d_in[12];
    const float* bd1   = (const float*)d_in[13];
    const float* Wd2   = (const float*)d_in[14];
    const float* bd2   = (const float*)d_in[15];

    char* ws = (char*)d_ws;
    float*    h_pre = (float*)(ws);
    float*    agg1  = (float*)(ws + 8000000);
    float*    agg2  = (float*)(ws + 16000000);
    float*    rs_s  = (float*)(ws + 24000000);
    float*    rs_r  = (float*)(ws + 24400000);
    unsigned* dS    = (unsigned*)(ws + 24800000);
    unsigned* dR    = (unsigned*)(ws + 25200000);
    float*    zbuf  = (float*)(ws + 25600000);

    float* X      = (float*)d_out;
    float* mu_out = X + (size_t)N_NODES * D_FEAT;                    // 25,600,000
    float* ls_out = mu_out + (size_t)N_NODES * Z_DIM;                // 28,800,000

    hipMemsetAsync(agg1, 0, 16000000, stream);   // agg1 + agg2
    hipMemsetAsync(dS,   0,   800000, stream);   // deg_s + deg_r

    k_deg<<<12500, 256, 0, stream>>>(snd, rcv, dS, dR);
    k_rs<<<391, 256, 0, stream>>>(dS, dR, rs_s, rs_r);
    k_gc1<<<2048, 256, 0, stream>>>(nodes, W1, b1, rs_s, h_pre);
    k_scatter<<<12500, 256, 0, stream>>>(snd, rcv, h_pre, agg1);
    k_gc2<<<391, 256, 0, stream>>>(agg1, W2, b2, rs_r, rs_s, h_pre); // h_pre := h2_pre
    k_scatter<<<12500, 256, 0, stream>>>(snd, rcv, h_pre, agg2);
    k_enc<<<391, 256, 0, stream>>>(agg2, nodes, eps, Wmu, bmu, Wls, bls, rs_r,
                                   mu_out, ls_out, zbuf);
    k_dec<<<391, 256, 0, stream>>>(zbuf, Wd1, bd1, Wd2, bd2, X);
}

// Round 2
// 1356.400 us; speedup vs baseline: 5.2864x; 5.2864x over previous
//
#include <hip/hip_runtime.h>
#include <math.h>

#define N_NODES 100000
#define N_EDGES 3200000
#define D_FEAT 256
#define GC_HID 20
#define DEC_HID 40
#define Z_DIM 32

// ---------------- ws layout (bytes) ----------------
// h_pre   : [N*20] f32 @ 0            (8,000,000)
// agg     : [N*20] f32 @  8,000,000   (8,000,000)
// z       : [N*32] f32 @ 16,000,000   (12,800,000)
// rs_s    : [N]    f32 @ 28,800,000
// rs_r    : [N]    f32 @ 29,200,000
// deg_s   : [N]    u32 @ 29,600,000
// deg_r   : [N]    u32 @ 30,000,000
// row_ptr : [N+1]  u32 @ 30,400,000
// cursor  : [N]    u32 @ 30,800,128
// edge_src: [E]    i32 @ 31,200,128   (12,800,000)  end = 44,000,128

__global__ void k_deg(const int* __restrict__ snd, const int* __restrict__ rcv,
                      unsigned* __restrict__ dS, unsigned* __restrict__ dR) {
    int e = blockIdx.x * 256 + threadIdx.x;
    if (e < N_EDGES) {
        atomicAdd(&dS[snd[e]], 1u);
        atomicAdd(&dR[rcv[e]], 1u);
    }
}

__global__ void k_rs(const unsigned* __restrict__ dS, const unsigned* __restrict__ dR,
                     float* __restrict__ rs_s, float* __restrict__ rs_r) {
    int i = blockIdx.x * 256 + threadIdx.x;
    if (i < N_NODES) {
        rs_s[i] = rsqrtf(fmaxf((float)dS[i], 1.0f));
        rs_r[i] = rsqrtf(fmaxf((float)dR[i], 1.0f));
    }
}

// exclusive scan of deg_r -> row_ptr[0..N], also copies into cursor
__global__ __launch_bounds__(1024) void k_scan(const unsigned* __restrict__ dR,
                                               unsigned* __restrict__ row_ptr,
                                               unsigned* __restrict__ cursor) {
    __shared__ unsigned part[1024];
    int t = threadIdx.x;
    const int CH = (N_NODES + 1023) / 1024;  // 98
    int lo = t * CH, hi = min(lo + CH, N_NODES);
    unsigned s = 0;
    for (int i = lo; i < hi; ++i) s += dR[i];
    part[t] = s;
    __syncthreads();
    for (int off = 1; off < 1024; off <<= 1) {
        unsigned v = (t >= off) ? part[t - off] : 0u;
        __syncthreads();
        part[t] += v;
        __syncthreads();
    }
    unsigned run = part[t] - s;  // exclusive prefix
    for (int i = lo; i < hi; ++i) {
        unsigned d = dR[i];
        row_ptr[i] = run;
        cursor[i] = run;
        run += d;
    }
    if (t == 1023) row_ptr[N_NODES] = run;
}

// CSR fill: edge_src[pos] = snd[e], pos from per-receiver cursor
__global__ void k_fill(const int* __restrict__ snd, const int* __restrict__ rcv,
                       unsigned* __restrict__ cursor, int* __restrict__ edge_src) {
    int e = blockIdx.x * 256 + threadIdx.x;
    if (e < N_EDGES) {
        unsigned pos = atomicAdd(&cursor[rcv[e]], 1u);
        edge_src[pos] = snd[e];
    }
}

// GC layer 1 transform: h_pre[n] = softmax(relu(nodes[n] @ W1 + b1)) * rs_s[n]
__global__ __launch_bounds__(256) void k_gc1(const float* __restrict__ nodes,
                                             const float* __restrict__ W1,
                                             const float* __restrict__ b1,
                                             const float* __restrict__ rs_s,
                                             float* __restrict__ h_pre) {
    __shared__ float Wt[GC_HID][D_FEAT];
    __shared__ float bsh[GC_HID];
    int tid = threadIdx.x;
    for (int idx = tid; idx < D_FEAT * GC_HID; idx += 256) {
        int i = idx / GC_HID, j = idx - i * GC_HID;
        Wt[j][i] = W1[idx];
    }
    if (tid < GC_HID) bsh[tid] = b1[tid];
    __syncthreads();

    int lane = tid & 63;
    int w    = tid >> 6;
    for (int node = blockIdx.x * 4 + w; node < N_NODES; node += gridDim.x * 4) {
        const float4 x = ((const float4*)nodes)[node * (D_FEAT / 4) + lane];
        float p[GC_HID];
#pragma unroll
        for (int j = 0; j < GC_HID; ++j) {
            float4 wv = ((const float4*)&Wt[j][0])[lane];
            p[j] = x.x * wv.x + x.y * wv.y + x.z * wv.z + x.w * wv.w;
        }
#pragma unroll
        for (int m = 32; m >= 1; m >>= 1) {
#pragma unroll
            for (int j = 0; j < GC_HID; ++j) p[j] += __shfl_xor(p[j], m, 64);
        }
        float mx = -1e30f;
#pragma unroll
        for (int j = 0; j < GC_HID; ++j) {
            p[j] = fmaxf(p[j] + bsh[j], 0.0f);
            mx = fmaxf(mx, p[j]);
        }
        float s = 0.0f;
#pragma unroll
        for (int j = 0; j < GC_HID; ++j) {
            p[j] = __expf(p[j] - mx);
            s += p[j];
        }
        float inv = rs_s[node] / s;
#pragma unroll
        for (int j = 0; j < GC_HID; ++j) p[j] *= inv;
        if (lane == 0) {
            float4* o = (float4*)&h_pre[node * GC_HID];
            o[0] = make_float4(p[0],  p[1],  p[2],  p[3]);
            o[1] = make_float4(p[4],  p[5],  p[6],  p[7]);
            o[2] = make_float4(p[8],  p[9],  p[10], p[11]);
            o[3] = make_float4(p[12], p[13], p[14], p[15]);
            o[4] = make_float4(p[16], p[17], p[18], p[19]);
        }
    }
}

// CSR gather: dst[n] = (sum over e in row_ptr[n..n+1) of src[edge_src[e]]) * rs_r[n]
// 5 threads per node, one float4 each.
__global__ __launch_bounds__(320) void k_gather(const unsigned* __restrict__ row_ptr,
                                                const int* __restrict__ edge_src,
                                                const float* __restrict__ src,
                                                const float* __restrict__ rs_r,
                                                float* __restrict__ dst) {
    int t = blockIdx.x * 320 + threadIdx.x;
    int node = t / 5, q = t % 5;
    if (node >= N_NODES) return;
    unsigned lo = row_ptr[node], hi = row_ptr[node + 1];
    float4 acc = make_float4(0.f, 0.f, 0.f, 0.f);
    for (unsigned e = lo; e < hi; ++e) {
        int s = edge_src[e];
        float4 v = ((const float4*)src)[s * 5 + q];
        acc.x += v.x; acc.y += v.y; acc.z += v.z; acc.w += v.w;
    }
    float sc = rs_r[node];
    acc.x *= sc; acc.y *= sc; acc.z *= sc; acc.w *= sc;
    ((float4*)dst)[node * 5 + q] = acc;
}

// GC layer 2 transform (input already rs_r-normalized): h2_pre = softmax(relu(h1@W2+b2))*rs_s
__global__ __launch_bounds__(256) void k_gc2(const float* __restrict__ h1in,
                                             const float* __restrict__ W2,
                                             const float* __restrict__ b2,
                                             const float* __restrict__ rs_s,
                                             float* __restrict__ h2_pre) {
    __shared__ float Wsh[GC_HID * GC_HID];
    __shared__ float bsh[GC_HID];
    int tid = threadIdx.x;
    if (tid < GC_HID * GC_HID) Wsh[tid] = W2[tid];
    if (tid < GC_HID) bsh[tid] = b2[tid];
    __syncthreads();
    int node = blockIdx.x * 256 + tid;
    if (node >= N_NODES) return;
    const float4* ap = (const float4*)&h1in[node * GC_HID];
    float4 a0 = ap[0], a1 = ap[1], a2 = ap[2], a3 = ap[3], a4 = ap[4];
    float h1[GC_HID] = {a0.x,a0.y,a0.z,a0.w, a1.x,a1.y,a1.z,a1.w,
                        a2.x,a2.y,a2.z,a2.w, a3.x,a3.y,a3.z,a3.w,
                        a4.x,a4.y,a4.z,a4.w};
    float t[GC_HID];
#pragma unroll
    for (int j = 0; j < GC_HID; ++j) t[j] = bsh[j];
#pragma unroll
    for (int i = 0; i < GC_HID; ++i) {
        float x = h1[i];
#pragma unroll
        for (int j = 0; j < GC_HID; ++j) t[j] = fmaf(x, Wsh[i * GC_HID + j], t[j]);
    }
    float mx = -1e30f;
#pragma unroll
    for (int j = 0; j < GC_HID; ++j) { t[j] = fmaxf(t[j], 0.0f); mx = fmaxf(mx, t[j]); }
    float s = 0.0f;
#pragma unroll
    for (int j = 0; j < GC_HID; ++j) { t[j] = __expf(t[j] - mx); s += t[j]; }
    float inv = rs_s[node] / s;
#pragma unroll
    for (int j = 0; j < GC_HID; ++j) t[j] *= inv;
    float4* o = (float4*)&h2_pre[node * GC_HID];
    o[0] = make_float4(t[0],  t[1],  t[2],  t[3]);
    o[1] = make_float4(t[4],  t[5],  t[6],  t[7]);
    o[2] = make_float4(t[8],  t[9],  t[10], t[11]);
    o[3] = make_float4(t[12], t[13], t[14], t[15]);
    o[4] = make_float4(t[16], t[17], t[18], t[19]);
}

// encoder head: h2 already normalized; hcat=[h2, nodes]; mu/logsig2; z
__global__ __launch_bounds__(256) void k_enc(const float* __restrict__ h2in,
                                             const float* __restrict__ nodes,
                                             const float* __restrict__ eps,
                                             const float* __restrict__ Wmu,
                                             const float* __restrict__ bmu,
                                             const float* __restrict__ Wls,
                                             const float* __restrict__ bls,
                                             float* __restrict__ mu_out,
                                             float* __restrict__ ls_out,
                                             float* __restrict__ z) {
    int node = blockIdx.x * 256 + threadIdx.x;
    if (node >= N_NODES) return;
    float accm[Z_DIM], accl[Z_DIM];
#pragma unroll
    for (int j = 0; j < Z_DIM; ++j) { accm[j] = bmu[j]; accl[j] = bls[j]; }

    const float4* ap = (const float4*)&h2in[node * GC_HID];
    float4 a0 = ap[0], a1 = ap[1], a2 = ap[2], a3 = ap[3], a4 = ap[4];
    float h2[GC_HID] = {a0.x,a0.y,a0.z,a0.w, a1.x,a1.y,a1.z,a1.w,
                        a2.x,a2.y,a2.z,a2.w, a3.x,a3.y,a3.z,a3.w,
                        a4.x,a4.y,a4.z,a4.w};
#pragma unroll
    for (int i = 0; i < GC_HID; ++i) {
        float x = h2[i];
#pragma unroll
        for (int j = 0; j < Z_DIM; ++j) {
            accm[j] = fmaf(x, Wmu[i * Z_DIM + j], accm[j]);
            accl[j] = fmaf(x, Wls[i * Z_DIM + j], accl[j]);
        }
    }
    const float4* np = (const float4*)&nodes[node * D_FEAT];
    for (int i4 = 0; i4 < D_FEAT / 4; ++i4) {
        float4 xx = np[i4];
        int row = GC_HID + i4 * 4;
#pragma unroll
        for (int c = 0; c < 4; ++c) {
            float x = (c == 0) ? xx.x : (c == 1) ? xx.y : (c == 2) ? xx.z : xx.w;
#pragma unroll
            for (int j = 0; j < Z_DIM; ++j) {
                accm[j] = fmaf(x, Wmu[(row + c) * Z_DIM + j], accm[j]);
                accl[j] = fmaf(x, Wls[(row + c) * Z_DIM + j], accl[j]);
            }
        }
    }
    const float4* ep = (const float4*)&eps[node * Z_DIM];
    float4* mo = (float4*)&mu_out[node * Z_DIM];
    float4* lo = (float4*)&ls_out[node * Z_DIM];
    float4* zo = (float4*)&z[node * Z_DIM];
#pragma unroll
    for (int q = 0; q < Z_DIM / 4; ++q) {
        float4 ev = ep[q];
        float4 m4 = make_float4(accm[4*q], accm[4*q+1], accm[4*q+2], accm[4*q+3]);
        float4 l4 = make_float4(accl[4*q], accl[4*q+1], accl[4*q+2], accl[4*q+3]);
        mo[q] = m4;
        lo[q] = l4;
        float4 zz;
        zz.x = m4.x + (1e-4f + __expf(0.5f * l4.x)) * ev.x;
        zz.y = m4.y + (1e-4f + __expf(0.5f * l4.y)) * ev.y;
        zz.z = m4.z + (1e-4f + __expf(0.5f * l4.z)) * ev.z;
        zz.w = m4.w + (1e-4f + __expf(0.5f * l4.w)) * ev.w;
        zo[q] = zz;
    }
}

// decoder: d = relu(z@Wd1+bd1); X = d@Wd2+bd2
__global__ __launch_bounds__(256) void k_dec(const float* __restrict__ z,
                                             const float* __restrict__ Wd1,
                                             const float* __restrict__ bd1,
                                             const float* __restrict__ Wd2,
                                             const float* __restrict__ bd2,
                                             float* __restrict__ X) {
    int node = blockIdx.x * 256 + threadIdx.x;
    if (node >= N_NODES) return;
    float zv[Z_DIM];
    const float4* zp = (const float4*)&z[node * Z_DIM];
#pragma unroll
    for (int q = 0; q < Z_DIM / 4; ++q) {
        float4 v = zp[q];
        zv[4*q] = v.x; zv[4*q+1] = v.y; zv[4*q+2] = v.z; zv[4*q+3] = v.w;
    }
    float d[DEC_HID];
#pragma unroll
    for (int j = 0; j < DEC_HID; ++j) d[j] = bd1[j];
#pragma unroll
    for (int i = 0; i < Z_DIM; ++i) {
        float x = zv[i];
#pragma unroll
        for (int j = 0; j < DEC_HID; ++j) d[j] = fmaf(x, Wd1[i * DEC_HID + j], d[j]);
    }
#pragma unroll
    for (int j = 0; j < DEC_HID; ++j) d[j] = fmaxf(d[j], 0.0f);

    float4* xp = (float4*)&X[node * D_FEAT];
    for (int ch = 0; ch < 4; ++ch) {
        float o[64];
#pragma unroll
        for (int j = 0; j < 64; ++j) o[j] = bd2[ch * 64 + j];
#pragma unroll
        for (int i = 0; i < DEC_HID; ++i) {
            float x = d[i];
#pragma unroll
            for (int j = 0; j < 64; ++j)
                o[j] = fmaf(x, Wd2[i * 256 + ch * 64 + j], o[j]);
        }
#pragma unroll
        for (int q = 0; q < 16; ++q)
            xp[ch * 16 + q] = make_float4(o[4*q], o[4*q+1], o[4*q+2], o[4*q+3]);
    }
}

extern "C" void kernel_launch(void* const* d_in, const int* in_sizes, int n_in,
                              void* d_out, int out_size, void* d_ws, size_t ws_size,
                              hipStream_t stream) {
    const float* nodes = (const float*)d_in[0];
    const int*   snd   = (const int*)d_in[1];
    const int*   rcv   = (const int*)d_in[2];
    const float* eps   = (const float*)d_in[3];
    const float* W1    = (const float*)d_in[4];
    const float* b1    = (const float*)d_in[5];
    const float* W2    = (const float*)d_in[6];
    const float* b2    = (const float*)d_in[7];
    const float* Wmu   = (const float*)d_in[8];
    const float* bmu   = (const float*)d_in[9];
    const float* Wls   = (const float*)d_in[10];
    const float* bls   = (const float*)d_in[11];
    const float* Wd1   = (const float*)d_in[12];
    const float* bd1   = (const float*)d_in[13];
    const float* Wd2   = (const float*)d_in[14];
    const float* bd2   = (const float*)d_in[15];

    char* ws = (char*)d_ws;
    float*    h_pre  = (float*)(ws);
    float*    agg    = (float*)(ws + 8000000);
    float*    zbuf   = (float*)(ws + 16000000);
    float*    rs_s   = (float*)(ws + 28800000);
    float*    rs_r   = (float*)(ws + 29200000);
    unsigned* dS     = (unsigned*)(ws + 29600000);
    unsigned* dR     = (unsigned*)(ws + 30000000);
    unsigned* rowp   = (unsigned*)(ws + 30400000);
    unsigned* cursor = (unsigned*)(ws + 30800128);
    int*      esrc   = (int*)(ws + 31200128);

    float* X      = (float*)d_out;
    float* mu_out = X + (size_t)N_NODES * D_FEAT;
    float* ls_out = mu_out + (size_t)N_NODES * Z_DIM;

    hipMemsetAsync(dS, 0, 800000, stream);   // deg_s + deg_r (contiguous)

    k_deg<<<12500, 256, 0, stream>>>(snd, rcv, dS, dR);
    k_rs<<<391, 256, 0, stream>>>(dS, dR, rs_s, rs_r);
    k_scan<<<1, 1024, 0, stream>>>(dR, rowp, cursor);
    k_fill<<<12500, 256, 0, stream>>>(snd, rcv, cursor, esrc);

    k_gc1<<<2048, 256, 0, stream>>>(nodes, W1, b1, rs_s, h_pre);
    k_gather<<<1563, 320, 0, stream>>>(rowp, esrc, h_pre, rs_r, agg);
    k_gc2<<<391, 256, 0, stream>>>(agg, W2, b2, rs_s, h_pre);
    k_gather<<<1563, 320, 0, stream>>>(rowp, esrc, h_pre, rs_r, agg);
    k_enc<<<391, 256, 0, stream>>>(agg, nodes, eps, Wmu, bmu, Wls, bls,
                                   mu_out, ls_out, zbuf);
    k_dec<<<391, 256, 0, stream>>>(zbuf, Wd1, bd1, Wd2, bd2, X);
}